// Round 17
// baseline (106.317 us; speedup 1.0000x reference)
//
#include <hip/hip_runtime.h>
#include <math.h>

#ifndef M_PI
#define M_PI 3.14159265358979323846
#endif

#define CTRL_ROW_SHR(n)  (0x110 | (n))
#define CTRL_ROW_ROR(n)  (0x120 | (n))
#define CTRL_ROW_BCAST15 0x142

// DPP move with old=0, bound_ctrl=0-fill. [green-proven R1/R8/R9/R15/R16]
template <int CTRL, int RM = 0xF>
__device__ __forceinline__ float dpp_mov0(float v) {
  return __int_as_float(__builtin_amdgcn_update_dpp(
      0, __float_as_int(v), CTRL, RM, 0xF, true));
}

// Inclusive prefix sum over each 32-lane half. VALU-only. [green-proven]
__device__ __forceinline__ float scan32_dpp(float v) {
  v += dpp_mov0<CTRL_ROW_SHR(1)>(v);
  v += dpp_mov0<CTRL_ROW_SHR(2)>(v);
  v += dpp_mov0<CTRL_ROW_SHR(4)>(v);
  v += dpp_mov0<CTRL_ROW_SHR(8)>(v);
  v += dpp_mov0<CTRL_ROW_BCAST15, 0xa>(v);  // rows 1,3 += lane15/47 prefix
  return v;
}

// Value of (lane-1) within the 32-group; garbage at s==0 (masked by callers).
__device__ __forceinline__ float shift1_dpp(float v, int s) {
  float a = dpp_mov0<CTRL_ROW_SHR(1)>(v);
  float b = dpp_mov0<CTRL_ROW_BCAST15, 0xa>(v);
  return (s == 16) ? b : a;
}

// Sum over the lane's 32-group, VALU-only (no DS): 4x row_ror rotate-add gives
// each lane its 16-row total; permlane16_swap exchanges 16-row halves within
// the 32-half; p[0]+p[1] = own + partner regardless of pairing direction.
// [R3==R4 bit-identity evidences the primitive computes consistent values;
//  the R3-R7 failures tracked the direct-global-load path, absent here.]
__device__ __forceinline__ float redsum32_valu(float v) {
  v += dpp_mov0<CTRL_ROW_ROR(8)>(v);
  v += dpp_mov0<CTRL_ROW_ROR(4)>(v);
  v += dpp_mov0<CTRL_ROW_ROR(2)>(v);
  v += dpp_mov0<CTRL_ROW_ROR(1)>(v);  // every lane: its 16-row total
#if __has_builtin(__builtin_amdgcn_permlane16_swap)
  typedef unsigned uint2_t __attribute__((ext_vector_type(2)));
  uint2_t p = __builtin_amdgcn_permlane16_swap(__float_as_uint(v),
                                               __float_as_uint(v), false, false);
  return __uint_as_float(p[0]) + __uint_as_float(p[1]);
#else
  float a = v, b = v;
  asm("v_permlane16_swap_b32 %0, %1" : "+v"(a), "+v"(b));
  return a + b;
#endif
}

// Fast reciprocal. [green-proven R16]
__device__ __forceinline__ float frcp(float x) { return __builtin_amdgcn_rcpf(x); }

// One wave handles 2 rows: lanes [0..23] -> row g=0, lanes [32..55] -> row g=1.
// = R16 green with the stats-lane LDS round-trip replaced by in-register
// two-pass instance norm (R8-proven structure) using the VALU-only reduction:
// DS issues/wave drop 84 -> 36; Phase C now writes NORMALIZED values.
__global__ __launch_bounds__(256) void feat_in_kernel(
    const float* __restrict__ x, float* __restrict__ out, int B) {
  constexpr float EPS = 1e-8f;
  constexpr float IN_EPS = 1e-5f;

  const int tid = threadIdx.x;
  const int wave = tid >> 6;
  const int lane = tid & 63;
  const int g = lane >> 5;   // row within wave
  const int s = lane & 31;   // timestep (active if < 24)

  __shared__ float lds[4][1200];  // 4800 B per wave
  float* Lw = lds[wave];

  const long long b0 = ((long long)blockIdx.x * 4 + wave) * 2;  // first row of wave
  long long rem = (long long)B - b0;
  int nrows = rem >= 2 ? 2 : (rem > 0 ? (int)rem : 0);

  // ---- Phase A: coalesced global -> LDS (nrows*30 float4) ---- [green]
  if (nrows > 0) {
    const float4* src4 = (const float4*)(x + b0 * 120);
    float4* L4 = (float4*)Lw;
    if (lane < nrows * 30) L4[lane] = src4[lane];
  }
  __syncthreads();

  const bool act = (s < 24) && (g < nrows);

  // ---- Phase B: per-lane feature computation ---- [green math]
  int ib = g * 120 + s * 5;
  float open_ = Lw[ib + 0];
  float high  = Lw[ib + 1];
  float low   = Lw[ib + 2];
  float close = Lw[ib + 3];
  float volume= Lw[ib + 4];
  if (!act) { open_ = 0.f; high = 0.f; low = 0.f; close = 1.f; volume = 0.f; }

  float f[23];

  float lc = __logf(close + EPS);
  float lc1 = shift1_dpp(lc, s);
  float ret = (s >= 1) ? (lc - lc1) : 0.f;

  f[0] = open_; f[1] = high; f[2] = low; f[3] = close; f[4] = volume;
  f[5] = ret;   f[6] = fabsf(ret);
  float ice = frcp(close + EPS);
  f[7] = (high - low) * ice;
  f[8] = fabsf(open_ - close) * ice;

  // EMAs: ema[s] = scan(x * beta^s) * (1-beta) / (1 - beta^(s+1))
  const float L2B3  = -1.0f;                    // log2(1/2)
  const float L2B6  = -0.48542682717024176f;    // log2(5/7)
  const float L2B12 = -0.24100810933089442f;    // log2(11/13)
  const float L2B24 = -0.12029423371771609f;    // log2(23/25)
  float sf = (float)s;
  float w3  = exp2f(L2B3  * sf);
  float w6  = exp2f(L2B6  * sf);
  float w12 = exp2f(L2B12 * sf);
  float w24 = exp2f(L2B24 * sf);

  float e3  = scan32_dpp(close * w3 ) * (0.5f         * frcp(1.f - w3  * 0.5f));
  float e6  = scan32_dpp(close * w6 ) * ((2.f / 7.f)  * frcp(1.f - w6  * (5.f / 7.f)));
  float e12 = scan32_dpp(close * w12) * ((2.f / 13.f) * frcp(1.f - w12 * (11.f / 13.f)));
  float e24 = scan32_dpp(close * w24) * ((2.f / 25.f) * frcp(1.f - w24 * (23.f / 25.f)));
  float v6  = scan32_dpp(volume * w6 ) * ((2.f / 7.f)  * frcp(1.f - w6  * (5.f / 7.f)));
  float v12 = scan32_dpp(volume * w12) * ((2.f / 13.f) * frcp(1.f - w12 * (11.f / 13.f)));

  float icl = frcp(close);
  f[9]  = e3  * icl;
  f[10] = e6  * icl;
  f[11] = e12 * icl;
  f[12] = e24 * icl;
  float iv = frcp(volume + EPS);
  f[13] = v6  * iv;
  f[14] = v12 * iv;
  f[15] = __logf(1.f + volume);

  float ang = (float)(M_PI / 12.0) * sf;  // 2*pi*s/24
  f[16] = __sinf(ang);
  f[17] = __cosf(ang);

  float lc3 = __shfl_up(lc, 3, 32);
  float lc6 = __shfl_up(lc, 6, 32);
  f[18] = (s >= 3) ? (lc - lc3) : 0.f;
  f[19] = (s >= 6) ? (lc - lc6) : 0.f;
  f[20] = (close - e12) * frcp(e12 + EPS);

  // RSI: window-14 moving average of gains/losses with left replicate-pad.
  float cl1 = shift1_dpp(close, s);
  float delta = (s >= 1) ? (close - cl1) : 0.f;
  float gain  = fmaxf(delta, 0.f);
  float lossv = fmaxf(-delta, 0.f);
  float Pg = scan32_dpp(gain);
  float Pl = scan32_dpp(lossv);
  float Pg14 = __shfl_up(Pg, 14, 32);
  float Pl14 = __shfl_up(Pl, 14, 32);
  float g1 = __shfl(gain, 1, 32);
  float l1 = __shfl(lossv, 1, 32);
  float cnt = (float)(14 - s);
  float ag = (s >= 14) ? (Pg - Pg14) : (Pg + cnt * g1);
  float al = (s >= 14) ? (Pl - Pl14) : (Pl + cnt * l1);
  ag *= (1.f / 14.f);
  al *= (1.f / 14.f);
  float rs  = ag * frcp(al + EPS);
  float rsi = 100.f - 100.f * frcp(1.f + rs);
  float rsi1 = __shfl(rsi, 1, 32);  // edge pad: rsi[0] = rsi at d=0
  f[21] = (s == 0) ? rsi1 : rsi;

  // OBV
  float mult = (delta > 0.f) ? 1.f : ((delta < 0.f) ? -1.f : 0.f);
  f[22] = scan32_dpp(volume * mult);

  // ---- Instance norm over s: two-pass, in registers, VALU-only reductions
  // (R8-proven structure; reduction primitive swapped shfl->permlane) ----
#pragma unroll
  for (int c = 0; c < 23; ++c) {
    float fm = act ? f[c] : 0.f;
    float mean = redsum32_valu(fm) * (1.f / 24.f);
    float dev = act ? (fm - mean) : 0.f;
    float var = redsum32_valu(dev * dev) * (1.f / 24.f);
    f[c] = dev * rsqrtf(var + IN_EPS);
  }

  // ---- Phase C: stage NORMALIZED features to LDS [g][s][25] ----
  __syncthreads();  // all lanes done reading the input staging region
  if (act) {
    int ob = g * 600 + s * 25;
#pragma unroll
    for (int c = 0; c < 23; c++) Lw[ob + c] = f[c];
    Lw[ob + 23] = 0.f;   // constant-over-s channels -> instance norm 0
    Lw[ob + 24] = 0.f;
  }
  __syncthreads();

  // ---- Phase D: coalesced LDS -> global (nrows*150 float4) ---- [green]
  if (nrows > 0) {
    float4* dst4 = (float4*)(out + b0 * 600);
    const float4* L4o = (const float4*)Lw;
    int n4 = nrows * 150;
#pragma unroll
    for (int k = lane; k < 300; k += 64) {
      if (k < n4) dst4[k] = L4o[k];
    }
  }
}

extern "C" void kernel_launch(void* const* d_in, const int* in_sizes, int n_in,
                              void* d_out, int out_size, void* d_ws, size_t ws_size,
                              hipStream_t stream) {
  const float* x = (const float*)d_in[0];
  float* out = (float*)d_out;
  int B = in_sizes[0] / 120;          // rows of (24,5)
  int blocks = (B + 7) / 8;           // 8 rows per 256-thread block (2 per wave)
  feat_in_kernel<<<blocks, 256, 0, stream>>>(x, out, B);
}

// Round 19
// 70.720 us; speedup vs baseline: 1.5034x; 1.5034x over previous
//
#include <hip/hip_runtime.h>
#include <math.h>

#ifndef M_PI
#define M_PI 3.14159265358979323846
#endif

#define CTRL_ROW_SHR(n)  (0x110 | (n))
#define CTRL_ROW_BCAST15 0x142

// Native 16B vector for nontemporal builtins (HIP_vector_type is rejected).
typedef float f4 __attribute__((ext_vector_type(4)));

// DPP move with old=0, bound_ctrl=0-fill. [green-proven R1/R8/R9/R15/R16]
template <int CTRL, int RM = 0xF>
__device__ __forceinline__ float dpp_mov0(float v) {
  return __int_as_float(__builtin_amdgcn_update_dpp(
      0, __float_as_int(v), CTRL, RM, 0xF, true));
}

// Inclusive prefix sum over each 32-lane half. VALU-only. [green-proven]
__device__ __forceinline__ float scan32_dpp(float v) {
  v += dpp_mov0<CTRL_ROW_SHR(1)>(v);
  v += dpp_mov0<CTRL_ROW_SHR(2)>(v);
  v += dpp_mov0<CTRL_ROW_SHR(4)>(v);
  v += dpp_mov0<CTRL_ROW_SHR(8)>(v);
  v += dpp_mov0<CTRL_ROW_BCAST15, 0xa>(v);  // rows 1,3 += lane15/47 prefix
  return v;
}

// Value of (lane-1) within the 32-group; garbage at s==0 (masked by callers).
__device__ __forceinline__ float shift1_dpp(float v, int s) {
  float a = dpp_mov0<CTRL_ROW_SHR(1)>(v);
  float b = dpp_mov0<CTRL_ROW_BCAST15, 0xa>(v);
  return (s == 16) ? b : a;
}

// Fast reciprocal. [green-proven R16]
__device__ __forceinline__ float frcp(float x) { return __builtin_amdgcn_rcpf(x); }

// One wave handles 2 rows: lanes [0..23] -> row g=0, lanes [32..55] -> row g=1.
// = R16 green (74.3us) with ONE change: nontemporal global load (Phase A) and
// nontemporal global stores (Phase D) via native ext_vector f4.
__global__ __launch_bounds__(256) void feat_in_kernel(
    const float* __restrict__ x, float* __restrict__ out, int B) {
  constexpr float EPS = 1e-8f;
  constexpr float IN_EPS = 1e-5f;

  const int tid = threadIdx.x;
  const int wave = tid >> 6;
  const int lane = tid & 63;
  const int g = lane >> 5;   // row within wave
  const int s = lane & 31;   // timestep (active if < 24)

  __shared__ float lds[4][1200];  // 4800 B per wave
  float* Lw = lds[wave];

  const long long b0 = ((long long)blockIdx.x * 4 + wave) * 2;  // first row of wave
  long long rem = (long long)B - b0;
  int nrows = rem >= 2 ? 2 : (rem > 0 ? (int)rem : 0);

  // ---- Phase A: coalesced global -> LDS (nrows*30 x 16B), nt load ----
  if (nrows > 0) {
    const f4* src4 = (const f4*)(x + b0 * 120);
    f4* L4 = (f4*)Lw;
    if (lane < nrows * 30) L4[lane] = __builtin_nontemporal_load(&src4[lane]);
  }
  __syncthreads();

  const bool act = (s < 24) && (g < nrows);

  // ---- Phase B: per-lane feature computation ---- [green math]
  int ib = g * 120 + s * 5;
  float open_ = Lw[ib + 0];
  float high  = Lw[ib + 1];
  float low   = Lw[ib + 2];
  float close = Lw[ib + 3];
  float volume= Lw[ib + 4];
  if (!act) { open_ = 0.f; high = 0.f; low = 0.f; close = 1.f; volume = 0.f; }

  float f[23];

  float lc = __logf(close + EPS);
  float lc1 = shift1_dpp(lc, s);
  float ret = (s >= 1) ? (lc - lc1) : 0.f;

  f[0] = open_; f[1] = high; f[2] = low; f[3] = close; f[4] = volume;
  f[5] = ret;   f[6] = fabsf(ret);
  float ice = frcp(close + EPS);
  f[7] = (high - low) * ice;
  f[8] = fabsf(open_ - close) * ice;

  // EMAs: ema[s] = scan(x * beta^s) * (1-beta) / (1 - beta^(s+1))
  const float L2B3  = -1.0f;                    // log2(1/2)
  const float L2B6  = -0.48542682717024176f;    // log2(5/7)
  const float L2B12 = -0.24100810933089442f;    // log2(11/13)
  const float L2B24 = -0.12029423371771609f;    // log2(23/25)
  float sf = (float)s;
  float w3  = exp2f(L2B3  * sf);
  float w6  = exp2f(L2B6  * sf);
  float w12 = exp2f(L2B12 * sf);
  float w24 = exp2f(L2B24 * sf);

  float e3  = scan32_dpp(close * w3 ) * (0.5f         * frcp(1.f - w3  * 0.5f));
  float e6  = scan32_dpp(close * w6 ) * ((2.f / 7.f)  * frcp(1.f - w6  * (5.f / 7.f)));
  float e12 = scan32_dpp(close * w12) * ((2.f / 13.f) * frcp(1.f - w12 * (11.f / 13.f)));
  float e24 = scan32_dpp(close * w24) * ((2.f / 25.f) * frcp(1.f - w24 * (23.f / 25.f)));
  float v6  = scan32_dpp(volume * w6 ) * ((2.f / 7.f)  * frcp(1.f - w6  * (5.f / 7.f)));
  float v12 = scan32_dpp(volume * w12) * ((2.f / 13.f) * frcp(1.f - w12 * (11.f / 13.f)));

  float icl = frcp(close);
  f[9]  = e3  * icl;
  f[10] = e6  * icl;
  f[11] = e12 * icl;
  f[12] = e24 * icl;
  float iv = frcp(volume + EPS);
  f[13] = v6  * iv;
  f[14] = v12 * iv;
  f[15] = __logf(1.f + volume);

  float ang = (float)(M_PI / 12.0) * sf;  // 2*pi*s/24
  f[16] = __sinf(ang);
  f[17] = __cosf(ang);

  float lc3 = __shfl_up(lc, 3, 32);
  float lc6 = __shfl_up(lc, 6, 32);
  f[18] = (s >= 3) ? (lc - lc3) : 0.f;
  f[19] = (s >= 6) ? (lc - lc6) : 0.f;
  f[20] = (close - e12) * frcp(e12 + EPS);

  // RSI: window-14 moving average of gains/losses with left replicate-pad.
  float cl1 = shift1_dpp(close, s);
  float delta = (s >= 1) ? (close - cl1) : 0.f;
  float gain  = fmaxf(delta, 0.f);
  float lossv = fmaxf(-delta, 0.f);
  float Pg = scan32_dpp(gain);
  float Pl = scan32_dpp(lossv);
  float Pg14 = __shfl_up(Pg, 14, 32);
  float Pl14 = __shfl_up(Pl, 14, 32);
  float g1 = __shfl(gain, 1, 32);
  float l1 = __shfl(lossv, 1, 32);
  float cnt = (float)(14 - s);
  float ag = (s >= 14) ? (Pg - Pg14) : (Pg + cnt * g1);
  float al = (s >= 14) ? (Pl - Pl14) : (Pl + cnt * l1);
  ag *= (1.f / 14.f);
  al *= (1.f / 14.f);
  float rs  = ag * frcp(al + EPS);
  float rsi = 100.f - 100.f * frcp(1.f + rs);
  float rsi1 = __shfl(rsi, 1, 32);  // edge pad: rsi[0] = rsi at d=0
  f[21] = (s == 0) ? rsi1 : rsi;

  // OBV
  float mult = (delta > 0.f) ? 1.f : ((delta < 0.f) ? -1.f : 0.f);
  f[22] = scan32_dpp(volume * mult);

  // ---- Phase C: stage RAW features to LDS in output layout [g][s][25];
  // ch23/24 (constant-over-s -> norm 0) written here so stats stay uniform ----
  __syncthreads();  // all lanes done reading the input staging region
  if (act) {
    int ob = g * 600 + s * 25;
#pragma unroll
    for (int c = 0; c < 23; c++) Lw[ob + c] = f[c];
    Lw[ob + 23] = 0.f;
    Lw[ob + 24] = 0.f;
  }
  __syncthreads();

  // ---- Stats phase: lanes 0..22 (g=0) and 25..47 (g=1), uniform branch ----
  if (lane < 50) {
    int gp = lane >= 25 ? 1 : 0;
    int cp = lane - gp * 25;
    if (cp < 23 && gp < nrows) {
      float* base = Lw + gp * 600 + cp;
      float vbuf[24];
#pragma unroll
      for (int s2 = 0; s2 < 24; ++s2) vbuf[s2] = base[s2 * 25];
      float sum = 0.f;
#pragma unroll
      for (int s2 = 0; s2 < 24; ++s2) sum += vbuf[s2];
      float mean = sum * (1.f / 24.f);
      float vs = 0.f;
#pragma unroll
      for (int s2 = 0; s2 < 24; ++s2) { float d = vbuf[s2] - mean; vs += d * d; }
      float rsig = rsqrtf(vs * (1.f / 24.f) + IN_EPS);
#pragma unroll
      for (int s2 = 0; s2 < 24; ++s2) base[s2 * 25] = (vbuf[s2] - mean) * rsig;
    }
  }
  __syncthreads();

  // ---- Phase D: coalesced LDS -> global (nrows*150 x 16B), nt stores ----
  if (nrows > 0) {
    f4* dst4 = (f4*)(out + b0 * 600);
    const f4* L4o = (const f4*)Lw;
    int n4 = nrows * 150;
#pragma unroll
    for (int k = lane; k < 300; k += 64) {
      if (k < n4) __builtin_nontemporal_store(L4o[k], &dst4[k]);
    }
  }
}

extern "C" void kernel_launch(void* const* d_in, const int* in_sizes, int n_in,
                              void* d_out, int out_size, void* d_ws, size_t ws_size,
                              hipStream_t stream) {
  const float* x = (const float*)d_in[0];
  float* out = (float*)d_out;
  int B = in_sizes[0] / 120;          // rows of (24,5)
  int blocks = (B + 7) / 8;           // 8 rows per 256-thread block (2 per wave)
  feat_in_kernel<<<blocks, 256, 0, stream>>>(x, out, B);
}